// Round 6
// baseline (233.554 us; speedup 1.0000x reference)
//
#include <hip/hip_runtime.h>
#include <hip/hip_bf16.h>
#include <hip/hip_fp16.h>
#include <cstdint>
#include <cstddef>

typedef _Float16 f16;
typedef f16 f16x2 __attribute__((ext_vector_type(2)));
typedef f16 f16x4 __attribute__((ext_vector_type(4)));
typedef f16 f16x8 __attribute__((ext_vector_type(8)));
typedef float f32x4 __attribute__((ext_vector_type(4)));

#define S_LEN 3072
#define DIM 1280
#define NH 16
#define HD 80
#define SEG 512

#define MFMA16F(a, b, c) __builtin_amdgcn_mfma_f32_16x16x32_f16((a), (b), (c), 0, 0, 0)

// async global->LDS, 16 B per lane; LDS dest = wave-uniform base + lane*16
__device__ __forceinline__ void gl2lds16(const void* g, void* l) {
    __builtin_amdgcn_global_load_lds(
        (const __attribute__((address_space(1))) unsigned int*)g,
        (__attribute__((address_space(3))) unsigned int*)l, 16, 0, 0);
}

__device__ __forceinline__ unsigned int pack2(float a, float b) {
    f16x2 t = {(f16)a, (f16)b};
    union { f16x2 v; unsigned int u; } c;
    c.v = t;
    return c.u;
}

// ---------------------------------------------------------------------------
// f32 -> f16 conversion of hs + 4 weight matrices (one dispatch, grid.y = mat)
// ---------------------------------------------------------------------------
__global__ __launch_bounds__(256) void cvt_kernel(
    const float* __restrict__ hs,
    const float* __restrict__ wq, const float* __restrict__ wk,
    const float* __restrict__ wv, const float* __restrict__ wo,
    f16* __restrict__ hs16,
    f16* __restrict__ wq16, f16* __restrict__ wk16,
    f16* __restrict__ wv16, f16* __restrict__ wo16)
{
    const int m = blockIdx.y;
    const float* src; f16* dst; int n4;
    if (m == 0)      { src = hs; dst = hs16; n4 = S_LEN * DIM / 4; }
    else if (m == 1) { src = wq; dst = wq16; n4 = DIM * DIM / 4; }
    else if (m == 2) { src = wk; dst = wk16; n4 = DIM * DIM / 4; }
    else if (m == 3) { src = wv; dst = wv16; n4 = DIM * DIM / 4; }
    else             { src = wo; dst = wo16; n4 = DIM * DIM / 4; }
    int idx = blockIdx.x * 256 + threadIdx.x;
    if (idx >= n4) return;
    f32x4 v = *(const f32x4*)(src + (size_t)idx * 4);
    f16x4 o;
#pragma unroll
    for (int e = 0; e < 4; ++e) o[e] = (f16)v[e];
    *(f16x4*)(dst + (size_t)idx * 4) = o;
}

// ---------------------------------------------------------------------------
// f16 GEMM v2: Out[row][col] = sum_k A[row][k]*W[col][k] + bias
// 128x128 tile, BK=64 as two m97-style BK=32 sub-tiles staged between ONE
// barrier pair (half the vmcnt(0)+barrier drains of BK=32). LDS 32 KB.
// mode = mode_base + blockIdx.z: 0,1,2 -> f16 out (q/k/v), 3 -> f32 d_out.
// ---------------------------------------------------------------------------
__global__ __launch_bounds__(256) void gemm_f16_kernel(
    const f16* __restrict__ A,
    const f16* __restrict__ W0, const f16* __restrict__ W1, const f16* __restrict__ W2,
    const float* __restrict__ b0, const float* __restrict__ b1, const float* __restrict__ b2,
    f16* __restrict__ O0, f16* __restrict__ O1, f16* __restrict__ O2,
    float* __restrict__ OF, int mode_base)
{
    const int mode = mode_base + blockIdx.z;
    const f16* W = (mode == 1) ? W1 : (mode == 2) ? W2 : W0;
    const float* bias = (mode == 1) ? b1 : (mode == 2) ? b2 : b0;

    __shared__ __align__(16) f16 As[2][128 * 32];
    __shared__ __align__(16) f16 Bs[2][128 * 32];

    const int tid = threadIdx.x;
    const int lane = tid & 63;
    const int lane15 = tid & 15;
    const int quad = lane >> 4;
    const int w = tid >> 6;
    const int wm = (w >> 1) * 64;
    const int wn = (w & 1) * 64;
    const int m0 = blockIdx.x * 128;
    const int n0 = blockIdx.y * 128;

    const int srow = w * 32 + (lane >> 2);
    const int scol = (lane & 3) * 8;
    const f16* gA0 = A + (size_t)(m0 + srow) * DIM + scol;
    const f16* gA1 = A + (size_t)(m0 + srow + 16) * DIM + scol;
    const f16* gB0 = W + (size_t)(n0 + srow) * DIM + scol;
    const f16* gB1 = W + (size_t)(n0 + srow + 16) * DIM + scol;
    f16* lA0 = &As[0][(w * 32) * 32];
    f16* lA1 = &As[0][(w * 32 + 16) * 32];
    f16* lB0 = &Bs[0][(w * 32) * 32];
    f16* lB1 = &Bs[0][(w * 32 + 16) * 32];
    const int half = 128 * 32;

    f32x4 acc[4][4];
#pragma unroll
    for (int i = 0; i < 4; ++i)
#pragma unroll
        for (int j = 0; j < 4; ++j)
            acc[i][j] = (f32x4){0.f, 0.f, 0.f, 0.f};

    for (int kt = 0; kt < DIM / 64; ++kt) {
        __syncthreads();
        // sub-tile 0: K range kt*64 .. +32
        gl2lds16(gA0 + kt * 64, lA0);
        gl2lds16(gA1 + kt * 64, lA1);
        gl2lds16(gB0 + kt * 64, lB0);
        gl2lds16(gB1 + kt * 64, lB1);
        // sub-tile 1: K range kt*64+32 .. +64
        gl2lds16(gA0 + kt * 64 + 32, lA0 + half);
        gl2lds16(gA1 + kt * 64 + 32, lA1 + half);
        gl2lds16(gB0 + kt * 64 + 32, lB0 + half);
        gl2lds16(gB1 + kt * 64 + 32, lB1 + half);
        __syncthreads();

#pragma unroll
        for (int s = 0; s < 2; ++s) {
            f16x8 fa[4], fb[4];
#pragma unroll
            for (int i = 0; i < 4; ++i)
                fa[i] = *(const f16x8*)(&As[s][(wm + i * 16 + lane15) * 32 + quad * 8]);
#pragma unroll
            for (int j = 0; j < 4; ++j)
                fb[j] = *(const f16x8*)(&Bs[s][(wn + j * 16 + lane15) * 32 + quad * 8]);
#pragma unroll
            for (int i = 0; i < 4; ++i)
#pragma unroll
                for (int j = 0; j < 4; ++j)
                    acc[i][j] = MFMA16F(fa[i], fb[j], acc[i][j]);
        }
    }

    float bvv[4];
#pragma unroll
    for (int j = 0; j < 4; ++j)
        bvv[j] = bias[n0 + wn + j * 16 + lane15];

    if (mode == 3) {
#pragma unroll
        for (int i = 0; i < 4; ++i)
#pragma unroll
            for (int j = 0; j < 4; ++j)
#pragma unroll
                for (int r = 0; r < 4; ++r) {
                    int row = m0 + wm + i * 16 + quad * 4 + r;
                    int col = n0 + wn + j * 16 + lane15;
                    OF[(size_t)row * DIM + col] = acc[i][j][r] + bvv[j];
                }
    } else {
        f16* O = (mode == 0) ? O0 : (mode == 1) ? O1 : O2;
#pragma unroll
        for (int i = 0; i < 4; ++i)
#pragma unroll
            for (int j = 0; j < 4; ++j)
#pragma unroll
                for (int r = 0; r < 4; ++r) {
                    int row = m0 + wm + i * 16 + quad * 4 + r;
                    int col = n0 + wn + j * 16 + lane15;
                    O[(size_t)row * DIM + col] = (f16)(acc[i][j][r] + bvv[j]);
                }
    }
}

// ---------------------------------------------------------------------------
// Merged prep: RoPE (blocks 0..1919) + V transpose (blocks 1920..2303).
// RoPE in place on f16 q,k (x8 vectorized), folds 80^-0.5 into q.
// vtrans: v16 [s][h*80+d] -> vT [h][d][s] via XOR-swizzled LDS tile.
// ---------------------------------------------------------------------------
__global__ __launch_bounds__(256) void prep_kernel(
    f16* __restrict__ qb, f16* __restrict__ kb,
    const float* __restrict__ cosb, const float* __restrict__ sinb,
    const f16* __restrict__ v, f16* __restrict__ vT)
{
    __shared__ __align__(16) f16 Ls[128 * 128];
    const int tid = threadIdx.x;
    if (blockIdx.x < 1920) {
        int idx = blockIdx.x * 256 + tid;    // 2*3072*16*5 = 491520 exact
        int c = idx % 5;
        int t = idx / 5;
        int h = t & 15; t >>= 4;
        int s = t % S_LEN;
        int which = t / S_LEN;
        f16* buf = which ? kb : qb;
        float scale = which ? 1.0f : 0.11180339887498948f;  // q pre-scaled
        int j = c * 8;
        f32x4 ca = *(const f32x4*)(cosb + s * HD + j);
        f32x4 cb = *(const f32x4*)(cosb + s * HD + j + 4);
        f32x4 sna = *(const f32x4*)(sinb + s * HD + j);
        f32x4 snb = *(const f32x4*)(sinb + s * HD + j + 4);
        size_t base = (size_t)s * DIM + h * HD + j;
        f16x8 x1 = *(f16x8*)(buf + base);
        f16x8 x2 = *(f16x8*)(buf + base + 40);
        f16x8 o1, o2;
#pragma unroll
        for (int e = 0; e < 8; ++e) {
            float ce = (e < 4) ? ca[e] : cb[e - 4];
            float se = (e < 4) ? sna[e] : snb[e - 4];
            float a = (float)x1[e], b = (float)x2[e];
            o1[e] = (f16)((a * ce - b * se) * scale);
            o2[e] = (f16)((b * ce + a * se) * scale);
        }
        *(f16x8*)(buf + base) = o1;
        *(f16x8*)(buf + base + 40) = o2;
    } else {
        int bid = blockIdx.x - 1920;
        const int h = bid / 24;
        const int s0 = (bid - h * 24) * 128;
#pragma unroll
        for (int c = tid; c < 1280; c += 256) {
            int r = c / 10;
            int ch = c - r * 10;                    // 16B chunk 0..9
            int chs = ch ^ ((r >> 3) & 7);          // swizzled chunk slot
            *(f16x8*)(Ls + r * 128 + chs * 8) =
                *(const f16x8*)(v + (size_t)(s0 + r) * DIM + h * HD + ch * 8);
        }
        __syncthreads();
#pragma unroll
        for (int c = tid; c < 1280; c += 256) {
            int d = c >> 4;
            int sc = c & 15;                        // s-chunk: s = sc*8+e
            f16x8 ov;
#pragma unroll
            for (int e = 0; e < 8; ++e) {
                int s = sc * 8 + e;
                ov[e] = Ls[s * 128 + (((d >> 3) ^ (sc & 7)) * 8) + (d & 7)];
            }
            *(f16x8*)(vT + (size_t)(h * HD + d) * S_LEN + s0 + sc * 8) = ov;
        }
    }
}

// ---------------------------------------------------------------------------
// Segment attention v3 (S^T trick). Block = (head, segment, 64-row q-chunk),
// 4 waves, wave owns 16 queries. Flash over 4 K-tiles of 128 keys.
// S^T = K*Q^T -> per-lane scalar softmax state, shfl_xor(16/32) reductions.
// PV: O^T = V^T * P^T; P^T B-frags assembled via packed-f16 shuffles.
// ---------------------------------------------------------------------------
__global__ __launch_bounds__(256) void attn_kernel(
    const f16* __restrict__ q, const f16* __restrict__ k,
    const f16* __restrict__ vT, f16* __restrict__ o)
{
    const int h = blockIdx.x;
    const int g = blockIdx.y;
    const int qc = blockIdx.z;
    const int tid = threadIdx.x;
    const int lane15 = tid & 15;
    const int quad = (tid & 63) >> 4;
    const int w = tid >> 6;
    const int qbase = g * SEG + qc * 64;
    const int qrow = qbase + w * 16 + lane15;

    __shared__ __align__(16) f16 Ks[128 * 88];   // K tile, rows padded to 88
    __shared__ __align__(16) f16 Vt[80 * 128];   // V^T tile, XOR-swizzled 16B chunks

    f16x8 zf;
#pragma unroll
    for (int e = 0; e < 8; ++e) zf[e] = (f16)0.0f;

    // Q as B-fragments (n=lane15=query, k=quad*8+j), in registers for all 4 kt
    f16x8 fq[3];
#pragma unroll
    for (int kc = 0; kc < 3; ++kc) {
        if (kc == 2 && quad >= 2) fq[kc] = zf;
        else fq[kc] = *(const f16x8*)(q + (size_t)qrow * DIM + h * HD + kc * 32 + quad * 8);
    }

    float m_run = -1e30f, l_run = 0.f;
    f32x4 Oa[5];
#pragma unroll
    for (int dt = 0; dt < 5; ++dt) Oa[dt] = (f32x4){0.f, 0.f, 0.f, 0.f};

    for (int kt = 0; kt < 4; ++kt) {
        __syncthreads();  // all waves done reading Ks/Vt from previous tile
        const int kb = g * SEG + kt * 128;
        // stage K tile (128 rows x 80 dims)
#pragma unroll
        for (int c = tid; c < 1280; c += 256) {
            int r = c / 10;
            int c8 = (c - r * 10) * 8;
            *(f16x8*)(Ks + r * 88 + c8) =
                *(const f16x8*)(k + (size_t)(kb + r) * DIM + h * HD + c8);
        }
        // stage V^T tile (80 dims x 128 keys), swizzled: chunk sc at slot sc^(d&7)
#pragma unroll
        for (int c = tid; c < 1280; c += 256) {
            int d = c >> 4;
            int sc = c & 15;
            *(f16x8*)(Vt + d * 128 + (sc ^ (d & 7)) * 8) =
                *(const f16x8*)(vT + (size_t)(h * HD + d) * S_LEN + kb + sc * 8);
        }
        __syncthreads();

        // S^T = K Q^T : 128 keys (8 m-tiles) x 16 queries
        f32x4 sa[8];
#pragma unroll
        for (int nt = 0; nt < 8; ++nt) sa[nt] = (f32x4){0.f, 0.f, 0.f, 0.f};
#pragma unroll
        for (int kc = 0; kc < 3; ++kc) {
#pragma unroll
            for (int nt = 0; nt < 8; ++nt) {
                f16x8 fk;
                if (kc == 2 && quad >= 2) fk = zf;
                else fk = *(const f16x8*)(Ks + (nt * 16 + lane15) * 88 + kc * 32 + quad * 8);
                sa[nt] = MFMA16F(fk, fq[kc], sa[nt]);
            }
        }

        // per-lane softmax over this lane's 32 key-scores (q = lane15 fixed)
        float mt = -1e30f;
#pragma unroll
        for (int nt = 0; nt < 8; ++nt)
#pragma unroll
            for (int r = 0; r < 4; ++r) mt = fmaxf(mt, sa[nt][r]);
        mt = fmaxf(mt, __shfl_xor(mt, 16, 64));
        mt = fmaxf(mt, __shfl_xor(mt, 32, 64));

        float mn = fmaxf(m_run, mt);
        float alpha = __expf(m_run - mn);
        m_run = mn;
        float lt = 0.f;
        unsigned int pp[8][2];   // packed f16 pairs of P^T
#pragma unroll
        for (int nt = 0; nt < 8; ++nt) {
            float p0 = __expf(sa[nt][0] - mn);
            float p1 = __expf(sa[nt][1] - mn);
            float p2 = __expf(sa[nt][2] - mn);
            float p3 = __expf(sa[nt][3] - mn);
            lt += (p0 + p1) + (p2 + p3);
            pp[nt][0] = pack2(p0, p1);
            pp[nt][1] = pack2(p2, p3);
        }
        lt += __shfl_xor(lt, 16, 64);
        lt += __shfl_xor(lt, 32, 64);
        l_run = l_run * alpha + lt;

#pragma unroll
        for (int dt = 0; dt < 5; ++dt)
#pragma unroll
            for (int r = 0; r < 4; ++r) Oa[dt][r] *= alpha;

        // PV: O^T = V^T P^T, 4 K-chunks of 32 keys
        const int srcA = ((quad & 1) * 2) * 16 + lane15;
        const int srcB = srcA + 16;
        const bool hi = quad >= 2;
#pragma unroll
        for (int kc2 = 0; kc2 < 4; ++kc2) {
            unsigned int e0 = __shfl((int)pp[2 * kc2][0], srcA, 64);
            unsigned int e1 = __shfl((int)pp[2 * kc2][1], srcA, 64);
            unsigned int e2 = __shfl((int)pp[2 * kc2][0], srcB, 64);
            unsigned int e3 = __shfl((int)pp[2 * kc2][1], srcB, 64);
            unsigned int o0 = __shfl((int)pp[2 * kc2 + 1][0], srcA, 64);
            unsigned int o1 = __shfl((int)pp[2 * kc2 + 1][1], srcA, 64);
            unsigned int o2 = __shfl((int)pp[2 * kc2 + 1][0], srcB, 64);
            unsigned int o3 = __shfl((int)pp[2 * kc2 + 1][1], srcB, 64);
            union { unsigned int u[4]; f16x8 v; } fp;
            fp.u[0] = hi ? o0 : e0;
            fp.u[1] = hi ? o1 : e1;
            fp.u[2] = hi ? o2 : e2;
            fp.u[3] = hi ? o3 : e3;
#pragma unroll
            for (int dt = 0; dt < 5; ++dt) {
                int drow = dt * 16 + lane15;
                int slot = (kc2 * 4 + quad) ^ (drow & 7);
                f16x8 fv = *(const f16x8*)(Vt + drow * 128 + slot * 8);
                Oa[dt] = MFMA16F(fv, fp.v, Oa[dt]);
            }
        }
    }

    // epilogue: normalize; O^T layout: d = dt*16 + quad*4 + r, query = lane15
    float inv = 1.0f / l_run;
#pragma unroll
    for (int dt = 0; dt < 5; ++dt) {
        f16x4 ov;
#pragma unroll
        for (int r = 0; r < 4; ++r) ov[r] = (f16)(Oa[dt][r] * inv);
        *(f16x4*)(o + (size_t)qrow * DIM + h * HD + dt * 16 + quad * 4) = ov;
    }
}

// ---------------------------------------------------------------------------
extern "C" void kernel_launch(void* const* d_in, const int* in_sizes, int n_in,
                              void* d_out, int out_size, void* d_ws, size_t ws_size,
                              hipStream_t stream)
{
    const float* hs   = (const float*)d_in[0];
    const float* cosb = (const float*)d_in[1];
    const float* sinb = (const float*)d_in[2];
    const float* wq   = (const float*)d_in[3];
    const float* bq   = (const float*)d_in[4];
    const float* wk   = (const float*)d_in[5];
    const float* bk   = (const float*)d_in[6];
    const float* wv   = (const float*)d_in[7];
    const float* bv   = (const float*)d_in[8];
    const float* wo   = (const float*)d_in[9];
    const float* bo   = (const float*)d_in[10];
    // d_in[11] = cu_seqlens: uniform 512-token segments by construction.

    const size_t SD = (size_t)S_LEN * DIM;   // 3.93M
    const size_t WW = (size_t)DIM * DIM;     // 1.64M
    f16* hs16 = (f16*)d_ws;
    f16* wq16 = hs16 + SD;
    f16* wk16 = wq16 + WW;
    f16* wv16 = wk16 + WW;
    f16* wo16 = wv16 + WW;
    f16* q16  = wo16 + WW;
    f16* k16  = q16 + SD;
    f16* v16  = k16 + SD;
    f16* ao16 = v16 + SD;
    f16* vT16 = ao16 + SD;                   // total ~60.3 MB
    float* outb = (float*)d_out;

    // f32 -> f16 prep (hs + 4 weights)
    cvt_kernel<<<dim3(S_LEN * DIM / 4 / 256, 5), 256, 0, stream>>>(
        hs, wq, wk, wv, wo, hs16, wq16, wk16, wv16, wo16);
    // fused QKV projection
    gemm_f16_kernel<<<dim3(24, 10, 3), 256, 0, stream>>>(
        hs16, wq16, wk16, wv16, bq, bk, bv, q16, k16, v16, nullptr, 0);
    // merged RoPE (q pre-scaled) + V transpose
    prep_kernel<<<2304, 256, 0, stream>>>(q16, k16, cosb, sinb, v16, vT16);
    // segment attention
    attn_kernel<<<dim3(NH, 6, 8), 256, 0, stream>>>(q16, k16, vT16, ao16);
    // output projection -> f32 d_out
    gemm_f16_kernel<<<dim3(24, 10, 1), 256, 0, stream>>>(
        ao16, wo16, nullptr, nullptr, bo, nullptr, nullptr,
        nullptr, nullptr, nullptr, outb, 3);
}

// Round 7
// 219.261 us; speedup vs baseline: 1.0652x; 1.0652x over previous
//
#include <hip/hip_runtime.h>
#include <hip/hip_bf16.h>
#include <hip/hip_fp16.h>
#include <cstdint>
#include <cstddef>

typedef _Float16 f16;
typedef f16 f16x2 __attribute__((ext_vector_type(2)));
typedef f16 f16x4 __attribute__((ext_vector_type(4)));
typedef f16 f16x8 __attribute__((ext_vector_type(8)));
typedef float f32x4 __attribute__((ext_vector_type(4)));

#define S_LEN 3072
#define DIM 1280
#define NH 16
#define HD 80
#define SEG 512

#define MFMA16F(a, b, c) __builtin_amdgcn_mfma_f32_16x16x32_f16((a), (b), (c), 0, 0, 0)

// async global->LDS, 16 B per lane; LDS dest = wave-uniform base + lane*16
__device__ __forceinline__ void gl2lds16(const void* g, void* l) {
    __builtin_amdgcn_global_load_lds(
        (const __attribute__((address_space(1))) unsigned int*)g,
        (__attribute__((address_space(3))) unsigned int*)l, 16, 0, 0);
}

__device__ __forceinline__ unsigned int pack2(float a, float b) {
    f16x2 t = {(f16)a, (f16)b};
    union { f16x2 v; unsigned int u; } c;
    c.v = t;
    return c.u;
}

// ---------------------------------------------------------------------------
// f32 -> f16 conversion of hs + 4 weight matrices (one dispatch, grid.y = mat)
// ---------------------------------------------------------------------------
__global__ __launch_bounds__(256) void cvt_kernel(
    const float* __restrict__ hs,
    const float* __restrict__ wq, const float* __restrict__ wk,
    const float* __restrict__ wv, const float* __restrict__ wo,
    f16* __restrict__ hs16,
    f16* __restrict__ wq16, f16* __restrict__ wk16,
    f16* __restrict__ wv16, f16* __restrict__ wo16)
{
    const int m = blockIdx.y;
    const float* src; f16* dst; int n4;
    if (m == 0)      { src = hs; dst = hs16; n4 = S_LEN * DIM / 4; }
    else if (m == 1) { src = wq; dst = wq16; n4 = DIM * DIM / 4; }
    else if (m == 2) { src = wk; dst = wk16; n4 = DIM * DIM / 4; }
    else if (m == 3) { src = wv; dst = wv16; n4 = DIM * DIM / 4; }
    else             { src = wo; dst = wo16; n4 = DIM * DIM / 4; }
    int idx = blockIdx.x * 256 + threadIdx.x;
    if (idx >= n4) return;
    f32x4 v = *(const f32x4*)(src + (size_t)idx * 4);
    f16x4 o;
#pragma unroll
    for (int e = 0; e < 4; ++e) o[e] = (f16)v[e];
    *(f16x4*)(dst + (size_t)idx * 4) = o;
}

// ---------------------------------------------------------------------------
// f16 QKV GEMM, m97 structure (BK=32 — BK=64 measured slower, m132-style):
// Out[row][col] = sum_k A[row][k]*W[col][k] + bias. 128x128 tile, 4 waves.
// blockIdx.z selects q/k/v weight set; f16 output.
// ---------------------------------------------------------------------------
__global__ __launch_bounds__(256) void gemm_f16_kernel(
    const f16* __restrict__ A,
    const f16* __restrict__ W0, const f16* __restrict__ W1, const f16* __restrict__ W2,
    const float* __restrict__ b0, const float* __restrict__ b1, const float* __restrict__ b2,
    f16* __restrict__ O0, f16* __restrict__ O1, f16* __restrict__ O2)
{
    const int mode = blockIdx.z;
    const f16* W = (mode == 1) ? W1 : (mode == 2) ? W2 : W0;
    const float* bias = (mode == 1) ? b1 : (mode == 2) ? b2 : b0;

    __shared__ __align__(16) f16 As[128 * 32];
    __shared__ __align__(16) f16 Bs[128 * 32];

    const int tid = threadIdx.x;
    const int lane = tid & 63;
    const int lane15 = tid & 15;
    const int quad = lane >> 4;
    const int w = tid >> 6;
    const int wm = (w >> 1) * 64;
    const int wn = (w & 1) * 64;
    const int m0 = blockIdx.x * 128;
    const int n0 = blockIdx.y * 128;

    const int srow = w * 32 + (lane >> 2);
    const int scol = (lane & 3) * 8;
    const f16* gA0 = A + (size_t)(m0 + srow) * DIM + scol;
    const f16* gA1 = A + (size_t)(m0 + srow + 16) * DIM + scol;
    const f16* gB0 = W + (size_t)(n0 + srow) * DIM + scol;
    const f16* gB1 = W + (size_t)(n0 + srow + 16) * DIM + scol;
    f16* lA0 = As + (w * 32) * 32;
    f16* lA1 = As + (w * 32 + 16) * 32;
    f16* lB0 = Bs + (w * 32) * 32;
    f16* lB1 = Bs + (w * 32 + 16) * 32;

    f32x4 acc[4][4];
#pragma unroll
    for (int i = 0; i < 4; ++i)
#pragma unroll
        for (int j = 0; j < 4; ++j)
            acc[i][j] = (f32x4){0.f, 0.f, 0.f, 0.f};

    for (int kt = 0; kt < DIM / 32; ++kt) {
        __syncthreads();
        gl2lds16(gA0 + kt * 32, lA0);
        gl2lds16(gA1 + kt * 32, lA1);
        gl2lds16(gB0 + kt * 32, lB0);
        gl2lds16(gB1 + kt * 32, lB1);
        __syncthreads();

        f16x8 fa[4], fb[4];
#pragma unroll
        for (int i = 0; i < 4; ++i)
            fa[i] = *(const f16x8*)(As + (wm + i * 16 + lane15) * 32 + quad * 8);
#pragma unroll
        for (int j = 0; j < 4; ++j)
            fb[j] = *(const f16x8*)(Bs + (wn + j * 16 + lane15) * 32 + quad * 8);
#pragma unroll
        for (int i = 0; i < 4; ++i)
#pragma unroll
            for (int j = 0; j < 4; ++j)
                acc[i][j] = MFMA16F(fa[i], fb[j], acc[i][j]);
    }

    float bvv[4];
#pragma unroll
    for (int j = 0; j < 4; ++j)
        bvv[j] = bias[n0 + wn + j * 16 + lane15];

    f16* O = (mode == 0) ? O0 : (mode == 1) ? O1 : O2;
#pragma unroll
    for (int i = 0; i < 4; ++i)
#pragma unroll
        for (int j = 0; j < 4; ++j)
#pragma unroll
            for (int r = 0; r < 4; ++r) {
                int row = m0 + wm + i * 16 + quad * 4 + r;
                int col = n0 + wn + j * 16 + lane15;
                O[(size_t)row * DIM + col] = (f16)(acc[i][j][r] + bvv[j]);
            }
}

// ---------------------------------------------------------------------------
// Out-projection GEMM, 64x128 tile -> grid 48x10=480 blocks (~1.9/CU; the
// 128x128 version gave only 240 blocks < 256 CUs = no latency hiding).
// 4 waves; wave = 64 rows x 32 cols (acc[4][2]); 3 gl2lds16/wave/iter.
// f32 output to d_out.
// ---------------------------------------------------------------------------
__global__ __launch_bounds__(256) void gemm_out_kernel(
    const f16* __restrict__ A, const f16* __restrict__ W,
    const float* __restrict__ bias, float* __restrict__ OF)
{
    __shared__ __align__(16) f16 As[64 * 32];
    __shared__ __align__(16) f16 Bs[128 * 32];

    const int tid = threadIdx.x;
    const int lane = tid & 63;
    const int lane15 = tid & 15;
    const int quad = lane >> 4;
    const int w = tid >> 6;
    const int wn = w * 32;
    const int m0 = blockIdx.x * 64;
    const int n0 = blockIdx.y * 128;

    const int srA = w * 16 + (lane >> 2);       // A rows: wave w covers 16 rows
    const int srB = w * 32 + (lane >> 2);       // B rows: wave w covers 32 rows
    const int scol = (lane & 3) * 8;
    const f16* gA0 = A + (size_t)(m0 + srA) * DIM + scol;
    const f16* gB0 = W + (size_t)(n0 + srB) * DIM + scol;
    const f16* gB1 = W + (size_t)(n0 + srB + 16) * DIM + scol;
    f16* lA0 = As + (w * 16) * 32;
    f16* lB0 = Bs + (w * 32) * 32;
    f16* lB1 = Bs + (w * 32 + 16) * 32;

    f32x4 acc[4][2];
#pragma unroll
    for (int i = 0; i < 4; ++i)
#pragma unroll
        for (int j = 0; j < 2; ++j)
            acc[i][j] = (f32x4){0.f, 0.f, 0.f, 0.f};

    for (int kt = 0; kt < DIM / 32; ++kt) {
        __syncthreads();
        gl2lds16(gA0 + kt * 32, lA0);
        gl2lds16(gB0 + kt * 32, lB0);
        gl2lds16(gB1 + kt * 32, lB1);
        __syncthreads();

        f16x8 fa[4], fb[2];
#pragma unroll
        for (int i = 0; i < 4; ++i)
            fa[i] = *(const f16x8*)(As + (i * 16 + lane15) * 32 + quad * 8);
#pragma unroll
        for (int j = 0; j < 2; ++j)
            fb[j] = *(const f16x8*)(Bs + (wn + j * 16 + lane15) * 32 + quad * 8);
#pragma unroll
        for (int i = 0; i < 4; ++i)
#pragma unroll
            for (int j = 0; j < 2; ++j)
                acc[i][j] = MFMA16F(fa[i], fb[j], acc[i][j]);
    }

    float bvv[2];
#pragma unroll
    for (int j = 0; j < 2; ++j)
        bvv[j] = bias[n0 + wn + j * 16 + lane15];

#pragma unroll
    for (int i = 0; i < 4; ++i)
#pragma unroll
        for (int j = 0; j < 2; ++j)
#pragma unroll
            for (int r = 0; r < 4; ++r) {
                int row = m0 + i * 16 + quad * 4 + r;
                int col = n0 + wn + j * 16 + lane15;
                OF[(size_t)row * DIM + col] = acc[i][j][r] + bvv[j];
            }
}

// ---------------------------------------------------------------------------
// Merged prep: RoPE (blocks 0..1919) + V transpose (blocks 1920..2303).
// RoPE in place on f16 q,k (x8 vectorized), folds 80^-0.5 into q.
// vtrans: v16 [s][h*80+d] -> vT [h][d][s] via XOR-swizzled LDS tile.
// ---------------------------------------------------------------------------
__global__ __launch_bounds__(256) void prep_kernel(
    f16* __restrict__ qb, f16* __restrict__ kb,
    const float* __restrict__ cosb, const float* __restrict__ sinb,
    const f16* __restrict__ v, f16* __restrict__ vT)
{
    __shared__ __align__(16) f16 Ls[128 * 128];
    const int tid = threadIdx.x;
    if (blockIdx.x < 1920) {
        int idx = blockIdx.x * 256 + tid;    // 2*3072*16*5 = 491520 exact
        int c = idx % 5;
        int t = idx / 5;
        int h = t & 15; t >>= 4;
        int s = t % S_LEN;
        int which = t / S_LEN;
        f16* buf = which ? kb : qb;
        float scale = which ? 1.0f : 0.11180339887498948f;  // q pre-scaled
        int j = c * 8;
        f32x4 ca = *(const f32x4*)(cosb + s * HD + j);
        f32x4 cb = *(const f32x4*)(cosb + s * HD + j + 4);
        f32x4 sna = *(const f32x4*)(sinb + s * HD + j);
        f32x4 snb = *(const f32x4*)(sinb + s * HD + j + 4);
        size_t base = (size_t)s * DIM + h * HD + j;
        f16x8 x1 = *(f16x8*)(buf + base);
        f16x8 x2 = *(f16x8*)(buf + base + 40);
        f16x8 o1, o2;
#pragma unroll
        for (int e = 0; e < 8; ++e) {
            float ce = (e < 4) ? ca[e] : cb[e - 4];
            float se = (e < 4) ? sna[e] : snb[e - 4];
            float a = (float)x1[e], b = (float)x2[e];
            o1[e] = (f16)((a * ce - b * se) * scale);
            o2[e] = (f16)((b * ce + a * se) * scale);
        }
        *(f16x8*)(buf + base) = o1;
        *(f16x8*)(buf + base + 40) = o2;
    } else {
        int bid = blockIdx.x - 1920;
        const int h = bid / 24;
        const int s0 = (bid - h * 24) * 128;
#pragma unroll
        for (int c = tid; c < 1280; c += 256) {
            int r = c / 10;
            int ch = c - r * 10;                    // 16B chunk 0..9
            int chs = ch ^ ((r >> 3) & 7);          // swizzled chunk slot
            *(f16x8*)(Ls + r * 128 + chs * 8) =
                *(const f16x8*)(v + (size_t)(s0 + r) * DIM + h * HD + ch * 8);
        }
        __syncthreads();
#pragma unroll
        for (int c = tid; c < 1280; c += 256) {
            int d = c >> 4;
            int sc = c & 15;                        // s-chunk: s = sc*8+e
            f16x8 ov;
#pragma unroll
            for (int e = 0; e < 8; ++e) {
                int s = sc * 8 + e;
                ov[e] = Ls[s * 128 + (((d >> 3) ^ (sc & 7)) * 8) + (d & 7)];
            }
            *(f16x8*)(vT + (size_t)(h * HD + d) * S_LEN + s0 + sc * 8) = ov;
        }
    }
}

// ---------------------------------------------------------------------------
// Segment attention v3 (S^T trick). Block = (head, segment, 64-row q-chunk),
// 4 waves, wave owns 16 queries. Flash over 4 K-tiles of 128 keys.
// S^T = K*Q^T -> per-lane scalar softmax state, shfl_xor(16/32) reductions.
// PV: O^T = V^T * P^T; P^T B-frags assembled via packed-f16 shuffles.
// ---------------------------------------------------------------------------
__global__ __launch_bounds__(256) void attn_kernel(
    const f16* __restrict__ q, const f16* __restrict__ k,
    const f16* __restrict__ vT, f16* __restrict__ o)
{
    const int h = blockIdx.x;
    const int g = blockIdx.y;
    const int qc = blockIdx.z;
    const int tid = threadIdx.x;
    const int lane15 = tid & 15;
    const int quad = (tid & 63) >> 4;
    const int w = tid >> 6;
    const int qbase = g * SEG + qc * 64;
    const int qrow = qbase + w * 16 + lane15;

    __shared__ __align__(16) f16 Ks[128 * 88];   // K tile, rows padded to 88
    __shared__ __align__(16) f16 Vt[80 * 128];   // V^T tile, XOR-swizzled 16B chunks

    f16x8 zf;
#pragma unroll
    for (int e = 0; e < 8; ++e) zf[e] = (f16)0.0f;

    // Q as B-fragments (n=lane15=query, k=quad*8+j), in registers for all 4 kt
    f16x8 fq[3];
#pragma unroll
    for (int kc = 0; kc < 3; ++kc) {
        if (kc == 2 && quad >= 2) fq[kc] = zf;
        else fq[kc] = *(const f16x8*)(q + (size_t)qrow * DIM + h * HD + kc * 32 + quad * 8);
    }

    float m_run = -1e30f, l_run = 0.f;
    f32x4 Oa[5];
#pragma unroll
    for (int dt = 0; dt < 5; ++dt) Oa[dt] = (f32x4){0.f, 0.f, 0.f, 0.f};

    for (int kt = 0; kt < 4; ++kt) {
        __syncthreads();  // all waves done reading Ks/Vt from previous tile
        const int kb = g * SEG + kt * 128;
        // stage K tile (128 rows x 80 dims)
#pragma unroll
        for (int c = tid; c < 1280; c += 256) {
            int r = c / 10;
            int c8 = (c - r * 10) * 8;
            *(f16x8*)(Ks + r * 88 + c8) =
                *(const f16x8*)(k + (size_t)(kb + r) * DIM + h * HD + c8);
        }
        // stage V^T tile (80 dims x 128 keys), swizzled: chunk sc at slot sc^(d&7)
#pragma unroll
        for (int c = tid; c < 1280; c += 256) {
            int d = c >> 4;
            int sc = c & 15;
            *(f16x8*)(Vt + d * 128 + (sc ^ (d & 7)) * 8) =
                *(const f16x8*)(vT + (size_t)(h * HD + d) * S_LEN + kb + sc * 8);
        }
        __syncthreads();

        // S^T = K Q^T : 128 keys (8 m-tiles) x 16 queries
        f32x4 sa[8];
#pragma unroll
        for (int nt = 0; nt < 8; ++nt) sa[nt] = (f32x4){0.f, 0.f, 0.f, 0.f};
#pragma unroll
        for (int kc = 0; kc < 3; ++kc) {
#pragma unroll
            for (int nt = 0; nt < 8; ++nt) {
                f16x8 fk;
                if (kc == 2 && quad >= 2) fk = zf;
                else fk = *(const f16x8*)(Ks + (nt * 16 + lane15) * 88 + kc * 32 + quad * 8);
                sa[nt] = MFMA16F(fk, fq[kc], sa[nt]);
            }
        }

        // per-lane softmax over this lane's 32 key-scores (q = lane15 fixed)
        float mt = -1e30f;
#pragma unroll
        for (int nt = 0; nt < 8; ++nt)
#pragma unroll
            for (int r = 0; r < 4; ++r) mt = fmaxf(mt, sa[nt][r]);
        mt = fmaxf(mt, __shfl_xor(mt, 16, 64));
        mt = fmaxf(mt, __shfl_xor(mt, 32, 64));

        float mn = fmaxf(m_run, mt);
        float alpha = __expf(m_run - mn);
        m_run = mn;
        float lt = 0.f;
        unsigned int pp[8][2];   // packed f16 pairs of P^T
#pragma unroll
        for (int nt = 0; nt < 8; ++nt) {
            float p0 = __expf(sa[nt][0] - mn);
            float p1 = __expf(sa[nt][1] - mn);
            float p2 = __expf(sa[nt][2] - mn);
            float p3 = __expf(sa[nt][3] - mn);
            lt += (p0 + p1) + (p2 + p3);
            pp[nt][0] = pack2(p0, p1);
            pp[nt][1] = pack2(p2, p3);
        }
        lt += __shfl_xor(lt, 16, 64);
        lt += __shfl_xor(lt, 32, 64);
        l_run = l_run * alpha + lt;

#pragma unroll
        for (int dt = 0; dt < 5; ++dt)
#pragma unroll
            for (int r = 0; r < 4; ++r) Oa[dt][r] *= alpha;

        // PV: O^T = V^T P^T, 4 K-chunks of 32 keys
        const int srcA = ((quad & 1) * 2) * 16 + lane15;
        const int srcB = srcA + 16;
        const bool hi = quad >= 2;
#pragma unroll
        for (int kc2 = 0; kc2 < 4; ++kc2) {
            unsigned int e0 = __shfl((int)pp[2 * kc2][0], srcA, 64);
            unsigned int e1 = __shfl((int)pp[2 * kc2][1], srcA, 64);
            unsigned int e2 = __shfl((int)pp[2 * kc2][0], srcB, 64);
            unsigned int e3 = __shfl((int)pp[2 * kc2][1], srcB, 64);
            unsigned int o0 = __shfl((int)pp[2 * kc2 + 1][0], srcA, 64);
            unsigned int o1 = __shfl((int)pp[2 * kc2 + 1][1], srcA, 64);
            unsigned int o2 = __shfl((int)pp[2 * kc2 + 1][0], srcB, 64);
            unsigned int o3 = __shfl((int)pp[2 * kc2 + 1][1], srcB, 64);
            union { unsigned int u[4]; f16x8 v; } fp;
            fp.u[0] = hi ? o0 : e0;
            fp.u[1] = hi ? o1 : e1;
            fp.u[2] = hi ? o2 : e2;
            fp.u[3] = hi ? o3 : e3;
#pragma unroll
            for (int dt = 0; dt < 5; ++dt) {
                int drow = dt * 16 + lane15;
                int slot = (kc2 * 4 + quad) ^ (drow & 7);
                f16x8 fv = *(const f16x8*)(Vt + drow * 128 + slot * 8);
                Oa[dt] = MFMA16F(fv, fp.v, Oa[dt]);
            }
        }
    }

    // epilogue: normalize; O^T layout: d = dt*16 + quad*4 + r, query = lane15
    float inv = 1.0f / l_run;
#pragma unroll
    for (int dt = 0; dt < 5; ++dt) {
        f16x4 ov;
#pragma unroll
        for (int r = 0; r < 4; ++r) ov[r] = (f16)(Oa[dt][r] * inv);
        *(f16x4*)(o + (size_t)qrow * DIM + h * HD + dt * 16 + quad * 4) = ov;
    }
}

// ---------------------------------------------------------------------------
extern "C" void kernel_launch(void* const* d_in, const int* in_sizes, int n_in,
                              void* d_out, int out_size, void* d_ws, size_t ws_size,
                              hipStream_t stream)
{
    const float* hs   = (const float*)d_in[0];
    const float* cosb = (const float*)d_in[1];
    const float* sinb = (const float*)d_in[2];
    const float* wq   = (const float*)d_in[3];
    const float* bq   = (const float*)d_in[4];
    const float* wk   = (const float*)d_in[5];
    const float* bk   = (const float*)d_in[6];
    const float* wv   = (const float*)d_in[7];
    const float* bv   = (const float*)d_in[8];
    const float* wo   = (const float*)d_in[9];
    const float* bo   = (const float*)d_in[10];
    // d_in[11] = cu_seqlens: uniform 512-token segments by construction.

    const size_t SD = (size_t)S_LEN * DIM;   // 3.93M
    const size_t WW = (size_t)DIM * DIM;     // 1.64M
    f16* hs16 = (f16*)d_ws;
    f16* wq16 = hs16 + SD;
    f16* wk16 = wq16 + WW;
    f16* wv16 = wk16 + WW;
    f16* wo16 = wv16 + WW;
    f16* q16  = wo16 + WW;
    f16* k16  = q16 + SD;
    f16* v16  = k16 + SD;
    f16* ao16 = v16 + SD;
    f16* vT16 = ao16 + SD;                   // total ~60.3 MB
    float* outb = (float*)d_out;

    // f32 -> f16 prep (hs + 4 weights)
    cvt_kernel<<<dim3(S_LEN * DIM / 4 / 256, 5), 256, 0, stream>>>(
        hs, wq, wk, wv, wo, hs16, wq16, wk16, wv16, wo16);
    // fused QKV projection (128x128 tile, BK=32)
    gemm_f16_kernel<<<dim3(24, 10, 3), 256, 0, stream>>>(
        hs16, wq16, wk16, wv16, bq, bk, bv, q16, k16, v16);
    // merged RoPE (q pre-scaled) + V transpose
    prep_kernel<<<2304, 256, 0, stream>>>(q16, k16, cosb, sinb, v16, vT16);
    // segment attention
    attn_kernel<<<dim3(NH, 6, 8), 256, 0, stream>>>(q16, k16, vT16, ao16);
    // output projection -> f32 d_out (64x128 tile, 480 blocks)
    gemm_out_kernel<<<dim3(48, 10), 256, 0, stream>>>(ao16, wo16, bo, outb);
}

// Round 8
// 217.669 us; speedup vs baseline: 1.0730x; 1.0073x over previous
//
#include <hip/hip_runtime.h>
#include <hip/hip_bf16.h>
#include <hip/hip_fp16.h>
#include <cstdint>
#include <cstddef>

typedef _Float16 f16;
typedef f16 f16x2 __attribute__((ext_vector_type(2)));
typedef f16 f16x4 __attribute__((ext_vector_type(4)));
typedef f16 f16x8 __attribute__((ext_vector_type(8)));
typedef float f32x4 __attribute__((ext_vector_type(4)));

#define S_LEN 3072
#define DIM 1280
#define NH 16
#define HD 80
#define SEG 512

#define MFMA16F(a, b, c) __builtin_amdgcn_mfma_f32_16x16x32_f16((a), (b), (c), 0, 0, 0)

// async global->LDS, 16 B per lane; LDS dest = wave-uniform base + lane*16
__device__ __forceinline__ void gl2lds16(const void* g, void* l) {
    __builtin_amdgcn_global_load_lds(
        (const __attribute__((address_space(1))) unsigned int*)g,
        (__attribute__((address_space(3))) unsigned int*)l, 16, 0, 0);
}

__device__ __forceinline__ unsigned int pack2(float a, float b) {
    f16x2 t = {(f16)a, (f16)b};
    union { f16x2 v; unsigned int u; } c;
    c.v = t;
    return c.u;
}

// ---------------------------------------------------------------------------
// f32 -> f16 conversion of hs + 4 weight matrices (one dispatch, grid.y = mat)
// ---------------------------------------------------------------------------
__global__ __launch_bounds__(256) void cvt_kernel(
    const float* __restrict__ hs,
    const float* __restrict__ wq, const float* __restrict__ wk,
    const float* __restrict__ wv, const float* __restrict__ wo,
    f16* __restrict__ hs16,
    f16* __restrict__ wq16, f16* __restrict__ wk16,
    f16* __restrict__ wv16, f16* __restrict__ wo16)
{
    const int m = blockIdx.y;
    const float* src; f16* dst; int n4;
    if (m == 0)      { src = hs; dst = hs16; n4 = S_LEN * DIM / 4; }
    else if (m == 1) { src = wq; dst = wq16; n4 = DIM * DIM / 4; }
    else if (m == 2) { src = wk; dst = wk16; n4 = DIM * DIM / 4; }
    else if (m == 3) { src = wv; dst = wv16; n4 = DIM * DIM / 4; }
    else             { src = wo; dst = wo16; n4 = DIM * DIM / 4; }
    int idx = blockIdx.x * 256 + threadIdx.x;
    if (idx >= n4) return;
    f32x4 v = *(const f32x4*)(src + (size_t)idx * 4);
    f16x4 o;
#pragma unroll
    for (int e = 0; e < 4; ++e) o[e] = (f16)v[e];
    *(f16x4*)(dst + (size_t)idx * 4) = o;
}

// ---------------------------------------------------------------------------
// f16 QKV GEMM, m97 structure (BK=32), XCD-swizzled flat grid (720 blocks):
// xcd = f&7 gets M-stripe {3*xcd..3*xcd+2} x all 30 (n,mode) tiles -> A-tiles
// stay L2-resident per XCD (~1 MB), B streams via L3.
// mode 0/1 -> q/k row-major f16; mode 2 -> V^T directly (vT[n][s]),
// eliminating the separate V-transpose pass.
// ---------------------------------------------------------------------------
__global__ __launch_bounds__(256) void gemm_f16_kernel(
    const f16* __restrict__ A,
    const f16* __restrict__ W0, const f16* __restrict__ W1, const f16* __restrict__ W2,
    const float* __restrict__ b0, const float* __restrict__ b1, const float* __restrict__ b2,
    f16* __restrict__ O0, f16* __restrict__ O1, f16* __restrict__ vT)
{
    const int f = blockIdx.x;            // 0..719
    const int xcd = f & 7;
    const int idx = f >> 3;              // 0..89
    const int mt = xcd * 3 + idx % 3;    // 0..23
    const int yz = idx / 3;              // 0..29
    const int nt = yz % 10;
    const int mode = yz / 10;            // 0,1,2

    const f16* W = (mode == 1) ? W1 : (mode == 2) ? W2 : W0;
    const float* bias = (mode == 1) ? b1 : (mode == 2) ? b2 : b0;

    __shared__ __align__(16) f16 As[128 * 32];
    __shared__ __align__(16) f16 Bs[128 * 32];

    const int tid = threadIdx.x;
    const int lane = tid & 63;
    const int lane15 = tid & 15;
    const int quad = lane >> 4;
    const int w = tid >> 6;
    const int wm = (w >> 1) * 64;
    const int wn = (w & 1) * 64;
    const int m0 = mt * 128;
    const int n0 = nt * 128;

    const int srow = w * 32 + (lane >> 2);
    const int scol = (lane & 3) * 8;
    const f16* gA0 = A + (size_t)(m0 + srow) * DIM + scol;
    const f16* gA1 = A + (size_t)(m0 + srow + 16) * DIM + scol;
    const f16* gB0 = W + (size_t)(n0 + srow) * DIM + scol;
    const f16* gB1 = W + (size_t)(n0 + srow + 16) * DIM + scol;
    f16* lA0 = As + (w * 32) * 32;
    f16* lA1 = As + (w * 32 + 16) * 32;
    f16* lB0 = Bs + (w * 32) * 32;
    f16* lB1 = Bs + (w * 32 + 16) * 32;

    f32x4 acc[4][4];
#pragma unroll
    for (int i = 0; i < 4; ++i)
#pragma unroll
        for (int j = 0; j < 4; ++j)
            acc[i][j] = (f32x4){0.f, 0.f, 0.f, 0.f};

    for (int kt = 0; kt < DIM / 32; ++kt) {
        __syncthreads();
        gl2lds16(gA0 + kt * 32, lA0);
        gl2lds16(gA1 + kt * 32, lA1);
        gl2lds16(gB0 + kt * 32, lB0);
        gl2lds16(gB1 + kt * 32, lB1);
        __syncthreads();

        f16x8 fa[4], fb[4];
#pragma unroll
        for (int i = 0; i < 4; ++i)
            fa[i] = *(const f16x8*)(As + (wm + i * 16 + lane15) * 32 + quad * 8);
#pragma unroll
        for (int j = 0; j < 4; ++j)
            fb[j] = *(const f16x8*)(Bs + (wn + j * 16 + lane15) * 32 + quad * 8);
#pragma unroll
        for (int i = 0; i < 4; ++i)
#pragma unroll
            for (int j = 0; j < 4; ++j)
                acc[i][j] = MFMA16F(fa[i], fb[j], acc[i][j]);
    }

    float bvv[4];
#pragma unroll
    for (int j = 0; j < 4; ++j)
        bvv[j] = bias[n0 + wn + j * 16 + lane15];

    if (mode == 2) {
        // V^T output: vT[col][row], C-rows (quad*4+r) contiguous -> f16x4
#pragma unroll
        for (int i = 0; i < 4; ++i)
#pragma unroll
            for (int j = 0; j < 4; ++j) {
                f16x4 ov;
#pragma unroll
                for (int r = 0; r < 4; ++r) ov[r] = (f16)(acc[i][j][r] + bvv[j]);
                int row = m0 + wm + i * 16 + quad * 4;
                int col = n0 + wn + j * 16 + lane15;
                *(f16x4*)(vT + (size_t)col * S_LEN + row) = ov;
            }
    } else {
        f16* O = (mode == 0) ? O0 : O1;
#pragma unroll
        for (int i = 0; i < 4; ++i)
#pragma unroll
            for (int j = 0; j < 4; ++j)
#pragma unroll
                for (int r = 0; r < 4; ++r) {
                    int row = m0 + wm + i * 16 + quad * 4 + r;
                    int col = n0 + wn + j * 16 + lane15;
                    O[(size_t)row * DIM + col] = (f16)(acc[i][j][r] + bvv[j]);
                }
    }
}

// ---------------------------------------------------------------------------
// Out-projection GEMM, 64x128 tile, XCD-swizzled flat grid (480 blocks):
// xcd gets M-stripe of 6 x-tiles x all 10 y. f32 output to d_out.
// ---------------------------------------------------------------------------
__global__ __launch_bounds__(256) void gemm_out_kernel(
    const f16* __restrict__ A, const f16* __restrict__ W,
    const float* __restrict__ bias, float* __restrict__ OF)
{
    const int f = blockIdx.x;          // 0..479
    const int xcd = f & 7;
    const int idx = f >> 3;            // 0..59
    const int xt = xcd * 6 + idx % 6;  // 0..47
    const int yt = idx / 6;            // 0..9

    __shared__ __align__(16) f16 As[64 * 32];
    __shared__ __align__(16) f16 Bs[128 * 32];

    const int tid = threadIdx.x;
    const int lane = tid & 63;
    const int lane15 = tid & 15;
    const int quad = lane >> 4;
    const int w = tid >> 6;
    const int wn = w * 32;
    const int m0 = xt * 64;
    const int n0 = yt * 128;

    const int srA = w * 16 + (lane >> 2);
    const int srB = w * 32 + (lane >> 2);
    const int scol = (lane & 3) * 8;
    const f16* gA0 = A + (size_t)(m0 + srA) * DIM + scol;
    const f16* gB0 = W + (size_t)(n0 + srB) * DIM + scol;
    const f16* gB1 = W + (size_t)(n0 + srB + 16) * DIM + scol;
    f16* lA0 = As + (w * 16) * 32;
    f16* lB0 = Bs + (w * 32) * 32;
    f16* lB1 = Bs + (w * 32 + 16) * 32;

    f32x4 acc[4][2];
#pragma unroll
    for (int i = 0; i < 4; ++i)
#pragma unroll
        for (int j = 0; j < 2; ++j)
            acc[i][j] = (f32x4){0.f, 0.f, 0.f, 0.f};

    for (int kt = 0; kt < DIM / 32; ++kt) {
        __syncthreads();
        gl2lds16(gA0 + kt * 32, lA0);
        gl2lds16(gB0 + kt * 32, lB0);
        gl2lds16(gB1 + kt * 32, lB1);
        __syncthreads();

        f16x8 fa[4], fb[2];
#pragma unroll
        for (int i = 0; i < 4; ++i)
            fa[i] = *(const f16x8*)(As + (i * 16 + lane15) * 32 + quad * 8);
#pragma unroll
        for (int j = 0; j < 2; ++j)
            fb[j] = *(const f16x8*)(Bs + (wn + j * 16 + lane15) * 32 + quad * 8);
#pragma unroll
        for (int i = 0; i < 4; ++i)
#pragma unroll
            for (int j = 0; j < 2; ++j)
                acc[i][j] = MFMA16F(fa[i], fb[j], acc[i][j]);
    }

    float bvv[2];
#pragma unroll
    for (int j = 0; j < 2; ++j)
        bvv[j] = bias[n0 + wn + j * 16 + lane15];

#pragma unroll
    for (int i = 0; i < 4; ++i)
#pragma unroll
        for (int j = 0; j < 2; ++j)
#pragma unroll
            for (int r = 0; r < 4; ++r) {
                int row = m0 + i * 16 + quad * 4 + r;
                int col = n0 + wn + j * 16 + lane15;
                OF[(size_t)row * DIM + col] = acc[i][j][r] + bvv[j];
            }
}

// ---------------------------------------------------------------------------
// RoPE in place on f16 q,k (x8 vectorized); folds 80^-0.5 into q.
// ---------------------------------------------------------------------------
__global__ __launch_bounds__(256) void rope_kernel(
    f16* __restrict__ qb, f16* __restrict__ kb,
    const float* __restrict__ cosb, const float* __restrict__ sinb)
{
    int idx = blockIdx.x * 256 + threadIdx.x;    // 2*3072*16*5 = 491520 exact
    int c = idx % 5;
    int t = idx / 5;
    int h = t & 15; t >>= 4;
    int s = t % S_LEN;
    int which = t / S_LEN;
    f16* buf = which ? kb : qb;
    float scale = which ? 1.0f : 0.11180339887498948f;  // q pre-scaled
    int j = c * 8;
    f32x4 ca = *(const f32x4*)(cosb + s * HD + j);
    f32x4 cb = *(const f32x4*)(cosb + s * HD + j + 4);
    f32x4 sna = *(const f32x4*)(sinb + s * HD + j);
    f32x4 snb = *(const f32x4*)(sinb + s * HD + j + 4);
    size_t base = (size_t)s * DIM + h * HD + j;
    f16x8 x1 = *(f16x8*)(buf + base);
    f16x8 x2 = *(f16x8*)(buf + base + 40);
    f16x8 o1, o2;
#pragma unroll
    for (int e = 0; e < 8; ++e) {
        float ce = (e < 4) ? ca[e] : cb[e - 4];
        float se = (e < 4) ? sna[e] : snb[e - 4];
        float a = (float)x1[e], b = (float)x2[e];
        o1[e] = (f16)((a * ce - b * se) * scale);
        o2[e] = (f16)((b * ce + a * se) * scale);
    }
    *(f16x8*)(buf + base) = o1;
    *(f16x8*)(buf + base + 40) = o2;
}

// ---------------------------------------------------------------------------
// Segment attention v3 (S^T trick). Block = (head, segment, 64-row q-chunk),
// 4 waves, wave owns 16 queries. Flash over 4 K-tiles of 128 keys.
// S^T = K*Q^T -> per-lane scalar softmax state, shfl_xor(16/32) reductions.
// PV: O^T = V^T * P^T; P^T B-frags assembled via packed-f16 shuffles.
// Note (h,g,qc) grid: qc-blocks sharing (h,g) are 96 apart in dispatch order,
// 96 % 8 == 0 -> same XCD under round-robin: K/V L2 reuse is already good.
// ---------------------------------------------------------------------------
__global__ __launch_bounds__(256) void attn_kernel(
    const f16* __restrict__ q, const f16* __restrict__ k,
    const f16* __restrict__ vT, f16* __restrict__ o)
{
    const int h = blockIdx.x;
    const int g = blockIdx.y;
    const int qc = blockIdx.z;
    const int tid = threadIdx.x;
    const int lane15 = tid & 15;
    const int quad = (tid & 63) >> 4;
    const int w = tid >> 6;
    const int qbase = g * SEG + qc * 64;
    const int qrow = qbase + w * 16 + lane15;

    __shared__ __align__(16) f16 Ks[128 * 88];   // K tile, rows padded to 88
    __shared__ __align__(16) f16 Vt[80 * 128];   // V^T tile, XOR-swizzled 16B chunks

    f16x8 zf;
#pragma unroll
    for (int e = 0; e < 8; ++e) zf[e] = (f16)0.0f;

    // Q as B-fragments (n=lane15=query, k=quad*8+j), in registers for all 4 kt
    f16x8 fq[3];
#pragma unroll
    for (int kc = 0; kc < 3; ++kc) {
        if (kc == 2 && quad >= 2) fq[kc] = zf;
        else fq[kc] = *(const f16x8*)(q + (size_t)qrow * DIM + h * HD + kc * 32 + quad * 8);
    }

    float m_run = -1e30f, l_run = 0.f;
    f32x4 Oa[5];
#pragma unroll
    for (int dt = 0; dt < 5; ++dt) Oa[dt] = (f32x4){0.f, 0.f, 0.f, 0.f};

    for (int kt = 0; kt < 4; ++kt) {
        __syncthreads();  // all waves done reading Ks/Vt from previous tile
        const int kb = g * SEG + kt * 128;
        // stage K tile (128 rows x 80 dims)
#pragma unroll
        for (int c = tid; c < 1280; c += 256) {
            int r = c / 10;
            int c8 = (c - r * 10) * 8;
            *(f16x8*)(Ks + r * 88 + c8) =
                *(const f16x8*)(k + (size_t)(kb + r) * DIM + h * HD + c8);
        }
        // stage V^T tile (80 dims x 128 keys), swizzled: chunk sc at slot sc^(d&7)
#pragma unroll
        for (int c = tid; c < 1280; c += 256) {
            int d = c >> 4;
            int sc = c & 15;
            *(f16x8*)(Vt + d * 128 + (sc ^ (d & 7)) * 8) =
                *(const f16x8*)(vT + (size_t)(h * HD + d) * S_LEN + kb + sc * 8);
        }
        __syncthreads();

        // S^T = K Q^T : 128 keys (8 m-tiles) x 16 queries
        f32x4 sa[8];
#pragma unroll
        for (int nt = 0; nt < 8; ++nt) sa[nt] = (f32x4){0.f, 0.f, 0.f, 0.f};
#pragma unroll
        for (int kc = 0; kc < 3; ++kc) {
#pragma unroll
            for (int nt = 0; nt < 8; ++nt) {
                f16x8 fk;
                if (kc == 2 && quad >= 2) fk = zf;
                else fk = *(const f16x8*)(Ks + (nt * 16 + lane15) * 88 + kc * 32 + quad * 8);
                sa[nt] = MFMA16F(fk, fq[kc], sa[nt]);
            }
        }

        // per-lane softmax over this lane's 32 key-scores (q = lane15 fixed)
        float mt = -1e30f;
#pragma unroll
        for (int nt = 0; nt < 8; ++nt)
#pragma unroll
            for (int r = 0; r < 4; ++r) mt = fmaxf(mt, sa[nt][r]);
        mt = fmaxf(mt, __shfl_xor(mt, 16, 64));
        mt = fmaxf(mt, __shfl_xor(mt, 32, 64));

        float mn = fmaxf(m_run, mt);
        float alpha = __expf(m_run - mn);
        m_run = mn;
        float lt = 0.f;
        unsigned int pp[8][2];   // packed f16 pairs of P^T
#pragma unroll
        for (int nt = 0; nt < 8; ++nt) {
            float p0 = __expf(sa[nt][0] - mn);
            float p1 = __expf(sa[nt][1] - mn);
            float p2 = __expf(sa[nt][2] - mn);
            float p3 = __expf(sa[nt][3] - mn);
            lt += (p0 + p1) + (p2 + p3);
            pp[nt][0] = pack2(p0, p1);
            pp[nt][1] = pack2(p2, p3);
        }
        lt += __shfl_xor(lt, 16, 64);
        lt += __shfl_xor(lt, 32, 64);
        l_run = l_run * alpha + lt;

#pragma unroll
        for (int dt = 0; dt < 5; ++dt)
#pragma unroll
            for (int r = 0; r < 4; ++r) Oa[dt][r] *= alpha;

        // PV: O^T = V^T P^T, 4 K-chunks of 32 keys
        const int srcA = ((quad & 1) * 2) * 16 + lane15;
        const int srcB = srcA + 16;
        const bool hi = quad >= 2;
#pragma unroll
        for (int kc2 = 0; kc2 < 4; ++kc2) {
            unsigned int e0 = __shfl((int)pp[2 * kc2][0], srcA, 64);
            unsigned int e1 = __shfl((int)pp[2 * kc2][1], srcA, 64);
            unsigned int e2 = __shfl((int)pp[2 * kc2][0], srcB, 64);
            unsigned int e3 = __shfl((int)pp[2 * kc2][1], srcB, 64);
            unsigned int o0 = __shfl((int)pp[2 * kc2 + 1][0], srcA, 64);
            unsigned int o1 = __shfl((int)pp[2 * kc2 + 1][1], srcA, 64);
            unsigned int o2 = __shfl((int)pp[2 * kc2 + 1][0], srcB, 64);
            unsigned int o3 = __shfl((int)pp[2 * kc2 + 1][1], srcB, 64);
            union { unsigned int u[4]; f16x8 v; } fp;
            fp.u[0] = hi ? o0 : e0;
            fp.u[1] = hi ? o1 : e1;
            fp.u[2] = hi ? o2 : e2;
            fp.u[3] = hi ? o3 : e3;
#pragma unroll
            for (int dt = 0; dt < 5; ++dt) {
                int drow = dt * 16 + lane15;
                int slot = (kc2 * 4 + quad) ^ (drow & 7);
                f16x8 fv = *(const f16x8*)(Vt + drow * 128 + slot * 8);
                Oa[dt] = MFMA16F(fv, fp.v, Oa[dt]);
            }
        }
    }

    // epilogue: normalize; O^T layout: d = dt*16 + quad*4 + r, query = lane15
    float inv = 1.0f / l_run;
#pragma unroll
    for (int dt = 0; dt < 5; ++dt) {
        f16x4 ov;
#pragma unroll
        for (int r = 0; r < 4; ++r) ov[r] = (f16)(Oa[dt][r] * inv);
        *(f16x4*)(o + (size_t)qrow * DIM + h * HD + dt * 16 + quad * 4) = ov;
    }
}

// ---------------------------------------------------------------------------
extern "C" void kernel_launch(void* const* d_in, const int* in_sizes, int n_in,
                              void* d_out, int out_size, void* d_ws, size_t ws_size,
                              hipStream_t stream)
{
    const float* hs   = (const float*)d_in[0];
    const float* cosb = (const float*)d_in[1];
    const float* sinb = (const float*)d_in[2];
    const float* wq   = (const float*)d_in[3];
    const float* bq   = (const float*)d_in[4];
    const float* wk   = (const float*)d_in[5];
    const float* bk   = (const float*)d_in[6];
    const float* wv   = (const float*)d_in[7];
    const float* bv   = (const float*)d_in[8];
    const float* wo   = (const float*)d_in[9];
    const float* bo   = (const float*)d_in[10];
    // d_in[11] = cu_seqlens: uniform 512-token segments by construction.

    const size_t SD = (size_t)S_LEN * DIM;   // 3.93M
    const size_t WW = (size_t)DIM * DIM;     // 1.64M
    f16* hs16 = (f16*)d_ws;
    f16* wq16 = hs16 + SD;
    f16* wk16 = wq16 + WW;
    f16* wv16 = wk16 + WW;
    f16* wo16 = wv16 + WW;
    f16* q16  = wo16 + WW;
    f16* k16  = q16 + SD;
    f16* vT16 = k16 + SD;                    // V^T written directly by GEMM
    f16* ao16 = vT16 + SD;                   // total ~52.4 MB
    float* outb = (float*)d_out;

    // f32 -> f16 prep (hs + 4 weights)
    cvt_kernel<<<dim3(S_LEN * DIM / 4 / 256, 5), 256, 0, stream>>>(
        hs, wq, wk, wv, wo, hs16, wq16, wk16, wv16, wo16);
    // fused QKV projection (XCD-swizzled flat grid; V written transposed)
    gemm_f16_kernel<<<720, 256, 0, stream>>>(
        hs16, wq16, wk16, wv16, bq, bk, bv, q16, k16, vT16);
    // RoPE in place (q gets 80^-0.5 folded in)
    rope_kernel<<<1920, 256, 0, stream>>>(q16, k16, cosb, sinb);
    // segment attention
    attn_kernel<<<dim3(NH, 6, 8), 256, 0, stream>>>(q16, k16, vT16, ao16);
    // output projection -> f32 d_out (64x128 tile, XCD-swizzled 480 blocks)
    gemm_out_kernel<<<480, 256, 0, stream>>>(ao16, wo16, bo, outb);
}